// Round 1
// 350.816 us; speedup vs baseline: 1.2779x; 1.2779x over previous
//
#include <hip/hip_runtime.h>
#include <cstdint>

#define S_DIM 128
#define L_DIM 512
#define INimD 256
#define OUTF  128

typedef __bf16 bf16x8 __attribute__((ext_vector_type(8)));
typedef float  f32x16 __attribute__((ext_vector_type(16)));

__device__ __forceinline__ unsigned short f2bf(float f) {
  // round-to-nearest-even f32 -> bf16 (inputs are finite/normal here)
  unsigned int u = __float_as_uint(f);
  u = (u + 0x7fffu + ((u >> 16) & 1u)) >> 16;
  return (unsigned short)u;
}

// ---------------- kernel 0: w_proj -> bf16 B-fragments ----------------------
// WP[((kt*2+nt)*64 + ln)*8 + jj] = bf16(w[j = nt*32 + (ln&31)][k = kt*16 + (ln>>5)*8 + jj])
// so a wave's B-frag load for (kt,nt) is one coalesced bf16x8 read per lane.
__global__ __launch_bounds__(256) void k_wp(const float* __restrict__ w,
                                            unsigned short* __restrict__ WP)
{
  const int gid = blockIdx.x * 256 + threadIdx.x;   // 0..2047
  const int ln = gid & 63, t = gid >> 6;            // t = kt*2+nt, 0..31
  const int nt = t & 1, kt = t >> 1;
  const int j  = nt * 32 + (ln & 31);
  const int k0 = kt * 16 + (ln >> 5) * 8;
#pragma unroll
  for (int jj = 0; jj < 8; ++jj)
    WP[(size_t)gid * 8 + jj] = f2bf(w[(size_t)j * INimD + k0 + jj]);
}

// ---------------- kernel 1: LayerNorm + MFMA projection + transpose ---------
// act[s,l,j] = (LN(x[s,l,:]) . w[j,:] + b[j]) * mask[s,l]
// l_t[(l*32+d)*128 + s] = bf16(act[s,l,d])       (d < 32)
// r_t[(l*32+e)*128 + s] = bf16(act[s,l,32+e])
// One block per l. Wave wv owns s-rows wv*32..wv*32+31 (its own MFMA M-tile),
// so LN-write -> A-frag-read needs no cross-wave dependency.
__global__ __launch_bounds__(256) void k_lnproj(
    const float* __restrict__ x, const float* __restrict__ mask,
    const unsigned short* __restrict__ WP, const float* __restrict__ b,
    unsigned short* __restrict__ l_t, unsigned short* __restrict__ r_t)
{
  __shared__ unsigned short smem[128 * 256];  // 64KB: xhat bf16 (XOR-swizzled rows); reused for act
  __shared__ float msk[128];
  const int tid = threadIdx.x;
  const int wv = tid >> 6, lane = tid & 63;
  const int half = lane >> 5, ln = lane & 31;
  const int l = blockIdx.x;

  if (tid < 128) msk[tid] = mask[(size_t)tid * L_DIM + l];

  // ---- LN: f32 stats, bf16 xhat into LDS. Swizzle: 16B-granule XOR of (row&7).
  for (int bi = 0; bi < 8; ++bi) {
    const int r0 = wv * 32 + bi * 4;
    float4 v[4];
#pragma unroll
    for (int q = 0; q < 4; ++q)
      v[q] = ((const float4*)(x + ((size_t)(r0 + q) * L_DIM + l) * INimD))[lane];
#pragma unroll
    for (int q = 0; q < 4; ++q) {
      float sm = v[q].x + v[q].y + v[q].z + v[q].w;
      float sq = v[q].x*v[q].x + v[q].y*v[q].y + v[q].z*v[q].z + v[q].w*v[q].w;
#pragma unroll
      for (int off = 32; off > 0; off >>= 1) {
        sm += __shfl_xor(sm, off);
        sq += __shfl_xor(sq, off);
      }
      const float mu  = sm * (1.0f / 256.0f);
      const float var = sq * (1.0f / 256.0f) - mu * mu;
      const float rs  = rsqrtf(var + 1e-5f);
      const int r = r0 + q;
      ushort4 hp;
      hp.x = f2bf((v[q].x - mu) * rs);
      hp.y = f2bf((v[q].y - mu) * rs);
      hp.z = f2bf((v[q].z - mu) * rs);
      hp.w = f2bf((v[q].w - mu) * rs);
      const int col = (lane * 4) ^ ((r & 7) << 3);     // u16 units
      *(ushort4*)&smem[r * 256 + col] = hp;
    }
  }
  __syncthreads();   // xs complete (and msk published)

  // ---- projection: act[s,:] = xhat[s,:] @ w^T via 32x32x16 bf16 MFMA
  // A-frag: lane holds xhat[row = wv*32 + (ln&31)][k = kt*16 + half*8 + jj]
  // B-frag (from WP): w[j = nt*32 + (ln&31)][same k]
  f32x16 acc0, acc1;
#pragma unroll
  for (int q = 0; q < 16; ++q) { acc0[q] = 0.f; acc1[q] = 0.f; }
  const int ar = wv * 32 + ln;
#pragma unroll
  for (int kt = 0; kt < 16; ++kt) {
    const int col = (kt * 16 + half * 8) ^ ((ln & 7) << 3);
    bf16x8 a  = *(const bf16x8*)&smem[ar * 256 + col];
    bf16x8 b0 = *(const bf16x8*)(WP + ((size_t)((kt * 2 + 0) * 64 + lane)) * 8);
    bf16x8 b1 = *(const bf16x8*)(WP + ((size_t)((kt * 2 + 1) * 64 + lane)) * 8);
    acc0 = __builtin_amdgcn_mfma_f32_32x32x16_bf16(a, b0, acc0, 0, 0, 0);
    acc1 = __builtin_amdgcn_mfma_f32_32x32x16_bf16(a, b1, acc1, 0, 0, 0);
  }
  __syncthreads();   // all xs reads done before act overwrites smem

  // ---- epilogue: C layout col=ln&31, row=(reg&3)+8*(reg>>2)+4*half
  // act region (reuses smem): [j(64)][s(128)] padded to 136
  unsigned short (*act)[136] = (unsigned short(*)[136])smem;
  const float bj0 = b[ln];
  const float bj1 = b[32 + ln];
#pragma unroll
  for (int nt = 0; nt < 2; ++nt) {
    const f32x16 a = nt ? acc1 : acc0;
    const float bj = nt ? bj1 : bj0;
    const int j = nt * 32 + ln;
#pragma unroll
    for (int g = 0; g < 4; ++g) {
      const int s0 = wv * 32 + g * 8 + half * 4;
      ushort4 p;
      p.x = f2bf((a[g*4+0] + bj) * msk[s0+0]);
      p.y = f2bf((a[g*4+1] + bj) * msk[s0+1]);
      p.z = f2bf((a[g*4+2] + bj) * msk[s0+2]);
      p.w = f2bf((a[g*4+3] + bj) * msk[s0+3]);
      *(ushort4*)&act[j][s0] = p;
    }
  }
  __syncthreads();

  // ---- coalesced transposed write-out: 4 threads per d-row, 32 s-elements each
  const int d = tid >> 2, c = (tid & 3) * 32;   // d in 0..63, c in {0,32,64,96}
  uint4 outv[4];
  ushort4* pv = (ushort4*)outv;
#pragma unroll
  for (int q = 0; q < 8; ++q) pv[q] = *(ushort4*)&act[d][c + q * 4];
  unsigned short* dst = (d < 32)
      ? (l_t + ((size_t)l * 32 + d) * S_DIM + c)
      : (r_t + ((size_t)l * 32 + (d - 32)) * S_DIM + c);
  ((uint4*)dst)[0] = outv[0];
  ((uint4*)dst)[1] = outv[1];
  ((uint4*)dst)[2] = outv[2];
  ((uint4*)dst)[3] = outv[3];
}

// ---------------- kernel 2: recip[i,j] = 1 / (mask^T mask + 0.001) -----------
__global__ __launch_bounds__(256) void k_norm(const float* __restrict__ mask,
                                              float* __restrict__ recip)
{
  const int i = blockIdx.y * 16 + (threadIdx.x >> 4);
  const int j = blockIdx.x * 16 + (threadIdx.x & 15);
  float acc = 0.f;
  for (int s = 0; s < S_DIM; ++s)
    acc += mask[(size_t)s * L_DIM + i] * mask[(size_t)s * L_DIM + j];
  recip[(size_t)i * L_DIM + j] = 1.0f / (acc + 0.001f);
}

// ---------------- kernel 3: W2 -> bf16, pre-swizzled into B-fragment order ---
// For k-step gkt (16 k's), f-tile ft (32 f's): lane holds Wt[f=ft*32+(lane&31)]
// [k = gkt*16 + (lane>>5)*8 + jj], stored contiguously -> coalesced wave loads.
__global__ __launch_bounds__(256) void k_wb(const float* __restrict__ W,
                                            unsigned short* __restrict__ WB)
{
  const int gid = blockIdx.x * 256 + threadIdx.x;   // 0..16383
  const int ln = gid & 63;
  const int ftkt = gid >> 6;                        // 0..255
  const int ft = ftkt & 3, kt = ftkt >> 2;
  const int f  = ft * 32 + (ln & 31);
  const int kb = kt * 16 + (ln >> 5) * 8;
#pragma unroll
  for (int jj = 0; jj < 8; ++jj) {
    const int k = kb + jj;                          // k = d*32 + e
    WB[(size_t)gid * 8 + jj] = f2bf(W[(size_t)k * OUTF + f]);
  }
}

// ---------------- kernel 4: fused pair-GEMM ---------------------------------
// Tile: 16 i x 4 j = 64 pairs per block. For each K-chunk (2 d's x 32 e = 64):
//  phase A: G[(ii,dc),(jl,e)] = sum_s l*r  (MFMA, K=s=128) -> bf16 -> g_lds
//  phase B: acc[pair, f] += G_chunk . W2_chunk  (MFMA, K=(d,e))
__global__ __launch_bounds__(256, 2) void k_pair(
    const unsigned short* __restrict__ l_t, const unsigned short* __restrict__ r_t,
    const unsigned short* __restrict__ WB, const float* __restrict__ recip,
    const float* __restrict__ bias, float* __restrict__ out)
{
  __shared__ __align__(16) unsigned short r_lds[128][136]; // (jl*32+e) x s
  __shared__ __align__(16) unsigned short l_lds[32][136];  // (dc*16+ii) x s
  __shared__ __align__(16) unsigned short g_lds[64][72];   // pair x kl(64)
  const int tid = threadIdx.x;
  const int wv = tid >> 6, lane = tid & 63;
  const int half = lane >> 5, ln = lane & 31;
  const int j0 = blockIdx.x * 4, i0 = blockIdx.y * 16;

  { // stage r tile once: r_t rows j0*32 .. j0*32+127; 2 thr/row, 64 u16 each
    const int row = tid >> 1, off = (tid & 1) * 64;
    const uint4* src = (const uint4*)(r_t + ((size_t)j0 * 32 + row) * S_DIM + off);
    uint4* dst = (uint4*)&r_lds[row][off];
#pragma unroll
    for (int q = 0; q < 8; ++q) dst[q] = src[q];   // 8 x 16B = 64 u16
  }

  f32x16 acc0, acc1;
#pragma unroll
  for (int q = 0; q < 16; ++q) { acc0[q] = 0.f; acc1[q] = 0.f; }

  for (int c = 0; c < 16; ++c) {        // d0 = 2*c
    { // stage l chunk: row = dc*16+ii  <-  l_t[(i0+ii)*32 + 2c+dc]
      const int row = tid >> 3, off = (tid & 7) * 16;
      const int ii = row & 15, dc = row >> 4;
      const uint4* src = (const uint4*)(l_t + (((size_t)(i0 + ii)) * 32 + 2 * c + dc) * S_DIM + off);
      uint4* dst = (uint4*)&l_lds[row][off];
      dst[0] = src[0]; dst[1] = src[1];
    }
    __syncthreads();   // l (and first-iter r) ready; fences prev phase-B g reads

    // ---- phase A: wave wv handles j-column tile jl = wv
    f32x16 g;
#pragma unroll
    for (int q = 0; q < 16; ++q) g[q] = 0.f;
#pragma unroll
    for (int s8 = 0; s8 < 8; ++s8) {
      const int soff = s8 * 16 + half * 8;
      bf16x8 a  = *(const bf16x8*)&l_lds[ln][soff];
      bf16x8 bb = *(const bf16x8*)&r_lds[wv * 32 + ln][soff];
      g = __builtin_amdgcn_mfma_f32_32x32x16_bf16(a, bb, g, 0, 0, 0);
    }
    __syncthreads();
    // C-layout -> g_lds[pair][kl]: row r=(reg&3)+8(reg>>2)+4*half, col e=ln
#pragma unroll
    for (int reg = 0; reg < 16; ++reg) {
      const int r  = (reg & 3) + 8 * (reg >> 2) + 4 * half; // = dc*16 + ii
      const int p  = (r & 15) * 4 + wv;                     // pair = ii*4 + jl
      const int kl = (r >> 4) * 32 + ln;                    // dc*32 + e
      g_lds[p][kl] = f2bf(g[reg]);
    }
    __syncthreads();

    // ---- phase B: wave wv owns f-strip [32*wv, 32*wv+32)
#pragma unroll
    for (int kt = 0; kt < 4; ++kt) {
      const int gkt = c * 4 + kt;
      bf16x8 bw = *(const bf16x8*)(WB + ((size_t)(gkt * 4 + wv) * 64 + lane) * 8);
      bf16x8 a0 = *(const bf16x8*)&g_lds[ln][kt * 16 + half * 8];
      bf16x8 a1 = *(const bf16x8*)&g_lds[32 + ln][kt * 16 + half * 8];
      acc0 = __builtin_amdgcn_mfma_f32_32x32x16_bf16(a0, bw, acc0, 0, 0, 0);
      acc1 = __builtin_amdgcn_mfma_f32_32x32x16_bf16(a1, bw, acc1, 0, 0, 0);
    }
  }

  // epilogue: D layout row=p(local), col=f; out[i,j,f] = (acc+bias[f])*recip[i,j]
  const float bi = bias[wv * 32 + ln];
#pragma unroll
  for (int mt = 0; mt < 2; ++mt) {
    const f32x16 a = mt ? acc1 : acc0;
#pragma unroll
    for (int reg = 0; reg < 16; ++reg) {
      const int p = mt * 32 + (reg & 3) + 8 * (reg >> 2) + 4 * half;
      const int i = i0 + (p >> 2), j = j0 + (p & 3);
      const float val = (a[reg] + bi) * recip[(size_t)i * L_DIM + j];
      out[((size_t)i * L_DIM + j) * OUTF + wv * 32 + ln] = val;
    }
  }
}

extern "C" void kernel_launch(void* const* d_in, const int* in_sizes, int n_in,
                              void* d_out, int out_size, void* d_ws, size_t ws_size,
                              hipStream_t stream) {
  const float* x    = (const float*)d_in[0];   // node_repr (128,512,256)
  const float* mask = (const float*)d_in[1];   // (128,512)
  const float* w    = (const float*)d_in[2];   // w_proj (64,256)
  const float* b    = (const float*)d_in[3];   // b_proj (64)
  const float* W    = (const float*)d_in[4];   // out_weights (32,32,128)
  const float* bias = (const float*)d_in[5];   // out_bias (128)
  float* out = (float*)d_out;

  char* ws = (char*)d_ws;
  unsigned short* l_t = (unsigned short*)ws;                         // 4 MB
  unsigned short* r_t = (unsigned short*)(ws + (4u << 20));          // 4 MB
  unsigned short* WB  = (unsigned short*)(ws + (8u << 20));          // 256 KB
  float* recip = (float*)(ws + (8u << 20) + (512u << 10));           // 1 MB
  unsigned short* WP  = (unsigned short*)(ws + (8u << 20) + (512u << 10) + (1u << 20)); // 32 KB

  hipLaunchKernelGGL(k_wp,     dim3(8),        dim3(256), 0, stream, w, WP);
  hipLaunchKernelGGL(k_lnproj, dim3(512),      dim3(256), 0, stream, x, mask, WP, b, l_t, r_t);
  hipLaunchKernelGGL(k_norm,   dim3(32, 32),   dim3(256), 0, stream, mask, recip);
  hipLaunchKernelGGL(k_wb,     dim3(64),       dim3(256), 0, stream, W, WB);
  hipLaunchKernelGGL(k_pair,   dim3(128, 32),  dim3(256), 0, stream, l_t, r_t, WB, recip, bias, out);
}

// Round 2
// 337.401 us; speedup vs baseline: 1.3287x; 1.0398x over previous
//
#include <hip/hip_runtime.h>
#include <cstdint>

#define S_DIM 128
#define L_DIM 512
#define INimD 256
#define OUTF  128

typedef __bf16 bf16x8 __attribute__((ext_vector_type(8)));
typedef __bf16 bf16x4 __attribute__((ext_vector_type(4)));
typedef float  f32x16 __attribute__((ext_vector_type(16)));

__device__ __forceinline__ unsigned short f2bf(float f) {
  // round-to-nearest-even f32 -> bf16 (inputs are finite/normal here)
  unsigned int u = __float_as_uint(f);
  u = (u + 0x7fffu + ((u >> 16) & 1u)) >> 16;
  return (unsigned short)u;
}

__device__ __forceinline__ void gload_lds16(const void* gsrc, void* ldst) {
  __builtin_amdgcn_global_load_lds(
      (const __attribute__((address_space(1))) unsigned int*)gsrc,
      (__attribute__((address_space(3))) unsigned int*)ldst, 16, 0, 0);
}

// ---------------- kernel 0: w_proj -> bf16 B-fragments ----------------------
__global__ __launch_bounds__(256) void k_wp(const float* __restrict__ w,
                                            unsigned short* __restrict__ WP)
{
  const int gid = blockIdx.x * 256 + threadIdx.x;   // 0..2047
  const int ln = gid & 63, t = gid >> 6;            // t = kt*2+nt, 0..31
  const int nt = t & 1, kt = t >> 1;
  const int j  = nt * 32 + (ln & 31);
  const int k0 = kt * 16 + (ln >> 5) * 8;
#pragma unroll
  for (int jj = 0; jj < 8; ++jj)
    WP[(size_t)gid * 8 + jj] = f2bf(w[(size_t)j * INimD + k0 + jj]);
}

// ---------------- kernel 1: LayerNorm + MFMA projection + transpose ---------
__global__ __launch_bounds__(256) void k_lnproj(
    const float* __restrict__ x, const float* __restrict__ mask,
    const unsigned short* __restrict__ WP, const float* __restrict__ b,
    unsigned short* __restrict__ l_t, unsigned short* __restrict__ r_t)
{
  __shared__ unsigned short smem[128 * 256];  // 64KB: xhat bf16 (XOR-swizzled rows); reused for act
  __shared__ float msk[128];
  const int tid = threadIdx.x;
  const int wv = tid >> 6, lane = tid & 63;
  const int half = lane >> 5, ln = lane & 31;
  const int l = blockIdx.x;

  if (tid < 128) msk[tid] = mask[(size_t)tid * L_DIM + l];

  for (int bi = 0; bi < 8; ++bi) {
    const int r0 = wv * 32 + bi * 4;
    float4 v[4];
#pragma unroll
    for (int q = 0; q < 4; ++q)
      v[q] = ((const float4*)(x + ((size_t)(r0 + q) * L_DIM + l) * INimD))[lane];
#pragma unroll
    for (int q = 0; q < 4; ++q) {
      float sm = v[q].x + v[q].y + v[q].z + v[q].w;
      float sq = v[q].x*v[q].x + v[q].y*v[q].y + v[q].z*v[q].z + v[q].w*v[q].w;
#pragma unroll
      for (int off = 32; off > 0; off >>= 1) {
        sm += __shfl_xor(sm, off);
        sq += __shfl_xor(sq, off);
      }
      const float mu  = sm * (1.0f / 256.0f);
      const float var = sq * (1.0f / 256.0f) - mu * mu;
      const float rs  = rsqrtf(var + 1e-5f);
      const int r = r0 + q;
      ushort4 hp;
      hp.x = f2bf((v[q].x - mu) * rs);
      hp.y = f2bf((v[q].y - mu) * rs);
      hp.z = f2bf((v[q].z - mu) * rs);
      hp.w = f2bf((v[q].w - mu) * rs);
      const int col = (lane * 4) ^ ((r & 7) << 3);     // u16 units
      *(ushort4*)&smem[r * 256 + col] = hp;
    }
  }
  __syncthreads();

  f32x16 acc0, acc1;
#pragma unroll
  for (int q = 0; q < 16; ++q) { acc0[q] = 0.f; acc1[q] = 0.f; }
  const int ar = wv * 32 + ln;
#pragma unroll
  for (int kt = 0; kt < 16; ++kt) {
    const int col = (kt * 16 + half * 8) ^ ((ln & 7) << 3);
    bf16x8 a  = *(const bf16x8*)&smem[ar * 256 + col];
    bf16x8 b0 = *(const bf16x8*)(WP + ((size_t)((kt * 2 + 0) * 64 + lane)) * 8);
    bf16x8 b1 = *(const bf16x8*)(WP + ((size_t)((kt * 2 + 1) * 64 + lane)) * 8);
    acc0 = __builtin_amdgcn_mfma_f32_32x32x16_bf16(a, b0, acc0, 0, 0, 0);
    acc1 = __builtin_amdgcn_mfma_f32_32x32x16_bf16(a, b1, acc1, 0, 0, 0);
  }
  __syncthreads();

  unsigned short (*act)[136] = (unsigned short(*)[136])smem;
  const float bj0 = b[ln];
  const float bj1 = b[32 + ln];
#pragma unroll
  for (int nt = 0; nt < 2; ++nt) {
    const f32x16 a = nt ? acc1 : acc0;
    const float bj = nt ? bj1 : bj0;
    const int j = nt * 32 + ln;
#pragma unroll
    for (int g = 0; g < 4; ++g) {
      const int s0 = wv * 32 + g * 8 + half * 4;
      ushort4 p;
      p.x = f2bf((a[g*4+0] + bj) * msk[s0+0]);
      p.y = f2bf((a[g*4+1] + bj) * msk[s0+1]);
      p.z = f2bf((a[g*4+2] + bj) * msk[s0+2]);
      p.w = f2bf((a[g*4+3] + bj) * msk[s0+3]);
      *(ushort4*)&act[j][s0] = p;
    }
  }
  __syncthreads();

  const int d = tid >> 2, c = (tid & 3) * 32;   // d in 0..63, c in {0,32,64,96}
  uint4 outv[4];
  ushort4* pv = (ushort4*)outv;
#pragma unroll
  for (int q = 0; q < 8; ++q) pv[q] = *(ushort4*)&act[d][c + q * 4];
  unsigned short* dst = (d < 32)
      ? (l_t + ((size_t)l * 32 + d) * S_DIM + c)
      : (r_t + ((size_t)l * 32 + (d - 32)) * S_DIM + c);
  ((uint4*)dst)[0] = outv[0];
  ((uint4*)dst)[1] = outv[1];
  ((uint4*)dst)[2] = outv[2];
  ((uint4*)dst)[3] = outv[3];
}

// ---------------- kernel 2: recip[i,j] = 1 / (mask^T mask + 0.001) -----------
// LDS-staged: block does a 16x16 tile; mask column slices staged once.
__global__ __launch_bounds__(256) void k_norm(const float* __restrict__ mask,
                                              float* __restrict__ recip)
{
  __shared__ float mi[128][16];
  __shared__ float mj[128][16];
  const int i0 = blockIdx.y * 16, j0 = blockIdx.x * 16;
  for (int idx = threadIdx.x; idx < 2048; idx += 256) {
    const int s = idx >> 4, cc = idx & 15;
    mi[s][cc] = mask[(size_t)s * L_DIM + i0 + cc];
    mj[s][cc] = mask[(size_t)s * L_DIM + j0 + cc];
  }
  __syncthreads();
  const int ti = threadIdx.x >> 4, tj = threadIdx.x & 15;
  float acc = 0.f;
#pragma unroll 8
  for (int s = 0; s < 128; ++s) acc += mi[s][ti] * mj[s][tj];
  recip[(size_t)(i0 + ti) * L_DIM + j0 + tj] = 1.0f / (acc + 0.001f);
}

// ---------------- kernel 3: W2 -> bf16, pre-swizzled into B-fragment order ---
__global__ __launch_bounds__(256) void k_wb(const float* __restrict__ W,
                                            unsigned short* __restrict__ WB)
{
  const int gid = blockIdx.x * 256 + threadIdx.x;   // 0..16383
  const int ln = gid & 63;
  const int ftkt = gid >> 6;                        // 0..255
  const int ft = ftkt & 3, kt = ftkt >> 2;
  const int f  = ft * 32 + (ln & 31);
  const int kb = kt * 16 + (ln >> 5) * 8;
#pragma unroll
  for (int jj = 0; jj < 8; ++jj) {
    const int k = kb + jj;                          // k = d*32 + e
    WB[(size_t)gid * 8 + jj] = f2bf(W[(size_t)k * OUTF + f]);
  }
}

// ---------------- kernel 4: fused pair-GEMM (v2) ----------------------------
// Tile: 16 i x 4 j = 64 pairs per block, f = 128.
// r held in registers as phase-A A-operand (loaded once).
// Phase A (swapped): G^layout = mfma(A=r, B=l): lane -> fixed pair, reg-quads ->
//   4 consecutive e -> 4x ds_write_b64 into g_lds (68-u16 row pad, conflict-free).
// Phase B: acc[pair][f] += G . W2 (2x b64 g reads, WB prefetched).
// Single barrier per K-chunk; l double-buffered (XOR-swizzled, global_load_lds
// with pre-swizzled per-lane source), g double-buffered.
__global__ __launch_bounds__(256, 3) void k_pair(
    const unsigned short* __restrict__ l_t, const unsigned short* __restrict__ r_t,
    const unsigned short* __restrict__ WB, const float* __restrict__ recip,
    const float* __restrict__ bias, float* __restrict__ out)
{
  __shared__ __align__(16) unsigned short l_lds[2][32][128]; // 16B-granule ^ (row&7)
  __shared__ __align__(16) unsigned short g_lds[2][64][68];  // pair x kl, padded
  const int tid = threadIdx.x;
  const int wv = tid >> 6, lane = tid & 63;
  const int half = lane >> 5, ln = lane & 31;
  const int j0 = blockIdx.x * 4, i0 = blockIdx.y * 16;

  // ---- r A-frags in registers: lane holds r_t[(j0+wv)*32 + ln][s8*16+half*8 ..+8)
  bf16x8 rf[8];
#pragma unroll
  for (int s8 = 0; s8 < 8; ++s8)
    rf[s8] = *(const bf16x8*)(r_t + ((size_t)(j0 + wv) * 32 + ln) * S_DIM
                                  + s8 * 16 + half * 8);

  // ---- staging sources for l (pre-swizzled per-lane global addr)
  // dest row r_ = wv*8 + t*4 + (lane>>4), dest granule gg = lane&15,
  // logical granule = gg ^ (r_&7); advances by 256 u16 (2 l_t rows) per c.
  const unsigned short* lsrc[2];
#pragma unroll
  for (int t = 0; t < 2; ++t) {
    const int r_ = wv * 8 + t * 4 + (lane >> 4);
    const int gg = lane & 15;
    lsrc[t] = l_t + ((size_t)(i0 + (r_ & 15)) * 32 + (r_ >> 4)) * S_DIM
                  + ((gg ^ (r_ & 7)) * 8);
  }
  // prologue: stage c=0 into buf 0
#pragma unroll
  for (int t = 0; t < 2; ++t)
    gload_lds16(lsrc[t], &l_lds[0][wv * 8 + t * 4][0]);

  f32x16 acc0, acc1;
#pragma unroll
  for (int q = 0; q < 16; ++q) { acc0[q] = 0.f; acc1[q] = 0.f; }

  const int pr  = (ln & 15) * 4 + wv;   // this lane's pair
  const int dcc = ln >> 4;              // this lane's dc

  __syncthreads();   // c=0 staging complete

  for (int c = 0; c < 16; ++c) {
    const int cur = c & 1;
    // issue stage for c+1 into the other buffer (overlaps phase A)
    if (c < 15) {
#pragma unroll
      for (int t = 0; t < 2; ++t) {
        lsrc[t] += 256;
        gload_lds16(lsrc[t], &l_lds[cur ^ 1][wv * 8 + t * 4][0]);
      }
    }
    // prefetch WB B-frags for this iter's phase B
    bf16x8 bw[4];
#pragma unroll
    for (int kt = 0; kt < 4; ++kt)
      bw[kt] = *(const bf16x8*)(WB + ((size_t)((c * 4 + kt) * 4 + wv) * 64 + lane) * 8);

    // ---- phase A: G = r . l  (A = r regs, B = l from LDS)
    f32x16 g;
#pragma unroll
    for (int q = 0; q < 16; ++q) g[q] = 0.f;
#pragma unroll
    for (int s8 = 0; s8 < 8; ++s8) {
      const int col = ((s8 * 2 + half) ^ (ln & 7)) * 8;  // swizzled u16 col
      bf16x8 bl = *(const bf16x8*)&l_lds[cur][ln][col];
      g = __builtin_amdgcn_mfma_f32_32x32x16_bf16(rf[s8], bl, g, 0, 0, 0);
    }
    // write G chunk: lane owns pair pr; reg-quad q -> kl = dcc*32 + 8q + 4half + {0..3}
    {
      unsigned short* gp = &g_lds[cur][pr][dcc * 32 + 4 * half];
#pragma unroll
      for (int q = 0; q < 4; ++q) {
        ushort4 hp;
        hp.x = f2bf(g[4*q+0]); hp.y = f2bf(g[4*q+1]);
        hp.z = f2bf(g[4*q+2]); hp.w = f2bf(g[4*q+3]);
        *(ushort4*)(gp + q * 8) = hp;
      }
    }
    __syncthreads();   // the single barrier: g visible, l[c+1] staged

    // ---- phase B: wave wv owns f-strip [32*wv, 32*wv+32)
#pragma unroll
    for (int kt = 0; kt < 4; ++kt) {
      const unsigned short* p0 = &g_lds[cur][ln][kt * 16 + half * 8];
      const unsigned short* p1 = &g_lds[cur][32 + ln][kt * 16 + half * 8];
      bf16x4 a0l = *(const bf16x4*)p0, a0h = *(const bf16x4*)(p0 + 4);
      bf16x4 a1l = *(const bf16x4*)p1, a1h = *(const bf16x4*)(p1 + 4);
      bf16x8 a0 = __builtin_shufflevector(a0l, a0h, 0,1,2,3,4,5,6,7);
      bf16x8 a1 = __builtin_shufflevector(a1l, a1h, 0,1,2,3,4,5,6,7);
      acc0 = __builtin_amdgcn_mfma_f32_32x32x16_bf16(a0, bw[kt], acc0, 0, 0, 0);
      acc1 = __builtin_amdgcn_mfma_f32_32x32x16_bf16(a1, bw[kt], acc1, 0, 0, 0);
    }
  }

  // epilogue: D layout row=p(local), col=f; out[i,j,f] = (acc+bias[f])*recip[i,j]
  const float bi = bias[wv * 32 + ln];
#pragma unroll
  for (int mt = 0; mt < 2; ++mt) {
    const f32x16 a = mt ? acc1 : acc0;
#pragma unroll
    for (int reg = 0; reg < 16; ++reg) {
      const int p = mt * 32 + (reg & 3) + 8 * (reg >> 2) + 4 * half;
      const int i = i0 + (p >> 2), j = j0 + (p & 3);
      const float val = (a[reg] + bi) * recip[(size_t)i * L_DIM + j];
      out[((size_t)i * L_DIM + j) * OUTF + wv * 32 + ln] = val;
    }
  }
}

extern "C" void kernel_launch(void* const* d_in, const int* in_sizes, int n_in,
                              void* d_out, int out_size, void* d_ws, size_t ws_size,
                              hipStream_t stream) {
  const float* x    = (const float*)d_in[0];   // node_repr (128,512,256)
  const float* mask = (const float*)d_in[1];   // (128,512)
  const float* w    = (const float*)d_in[2];   // w_proj (64,256)
  const float* b    = (const float*)d_in[3];   // b_proj (64)
  const float* W    = (const float*)d_in[4];   // out_weights (32,32,128)
  const float* bias = (const float*)d_in[5];   // out_bias (128)
  float* out = (float*)d_out;

  char* ws = (char*)d_ws;
  unsigned short* l_t = (unsigned short*)ws;                         // 4 MB
  unsigned short* r_t = (unsigned short*)(ws + (4u << 20));          // 4 MB
  unsigned short* WB  = (unsigned short*)(ws + (8u << 20));          // 256 KB
  float* recip = (float*)(ws + (8u << 20) + (512u << 10));           // 1 MB
  unsigned short* WP  = (unsigned short*)(ws + (8u << 20) + (512u << 10) + (1u << 20)); // 32 KB

  hipLaunchKernelGGL(k_wp,     dim3(8),        dim3(256), 0, stream, w, WP);
  hipLaunchKernelGGL(k_lnproj, dim3(512),      dim3(256), 0, stream, x, mask, WP, b, l_t, r_t);
  hipLaunchKernelGGL(k_norm,   dim3(32, 32),   dim3(256), 0, stream, mask, recip);
  hipLaunchKernelGGL(k_wb,     dim3(64),       dim3(256), 0, stream, W, WB);
  hipLaunchKernelGGL(k_pair,   dim3(128, 32),  dim3(256), 0, stream, l_t, r_t, WB, recip, bias, out);
}